// Round 1
// baseline (330.658 us; speedup 1.0000x reference)
//
#include <hip/hip_runtime.h>

// IDWT2D db4, periodized. Input x: [64][256][256][16] f32 (cA|cH|cV|cD x 4ch),
// output: [64][512][512][4] f32.
//
// out[b, 2jy+py, 2jx+px, ch] =
//   sum_{sy,sx=0..3} Lx[px][sx]*(Ly[py][sy]*cA + Hy[py][sy]*cH)
//                  + Hx[px][sx]*(Ly[py][sy]*cV + Hy[py][sy]*cD)
//   at input pixel ((jy+sy)&255, (jx+sx)&255).

__global__ __launch_bounds__(256) void idwt2_db4_kernel(
    const float* __restrict__ x, float* __restrict__ out) {
  constexpr int N = 256;  // input spatial size

  constexpr float LO[8] = {
      0.23037781330885523f,  0.7148465705525415f,  0.6308807679295904f,
      -0.02798376941698385f, -0.18703481171888114f, 0.030841381835986965f,
      0.032883011666982945f, -0.010597401784997278f};
  constexpr float HIW[8] = {
      -0.010597401784997278f, -0.032883011666982945f, 0.030841381835986965f,
      0.18703481171888114f,  -0.02798376941698385f,  -0.6308807679295904f,
      0.7148465705525415f,   -0.23037781330885523f};

  // W[parity][s] applied to coeff index (j+s)&255
  const float Lw[2][4] = {{LO[6], LO[4], LO[2], LO[0]},
                          {LO[7], LO[5], LO[3], LO[1]}};
  const float Hw[2][4] = {{HIW[6], HIW[4], HIW[2], HIW[0]},
                          {HIW[7], HIW[5], HIW[3], HIW[1]}};

  const int idx = blockIdx.x * blockDim.x + threadIdx.x;
  const int jx = idx & (N - 1);
  const int jy = (idx >> 8) & (N - 1);
  const int b = idx >> 16;

  // Input pixel = 4 float4 (cA, cH, cV, cD).
  const float4* xb = reinterpret_cast<const float4*>(x) + (size_t)b * N * N * 4;

  float acc[2][2][4];
#pragma unroll
  for (int p = 0; p < 2; ++p)
#pragma unroll
    for (int q = 0; q < 2; ++q)
#pragma unroll
      for (int c = 0; c < 4; ++c) acc[p][q][c] = 0.0f;

#pragma unroll
  for (int sx = 0; sx < 4; ++sx) {
    const int xx = (jx + sx) & (N - 1);
    float lo[2][4], hi[2][4];
#pragma unroll
    for (int p = 0; p < 2; ++p)
#pragma unroll
      for (int c = 0; c < 4; ++c) {
        lo[p][c] = 0.0f;
        hi[p][c] = 0.0f;
      }

#pragma unroll
    for (int sy = 0; sy < 4; ++sy) {
      const int yy = (jy + sy) & (N - 1);
      const float4* p4 = xb + ((size_t)yy * N + xx) * 4;
      const float4 a = p4[0];
      const float4 h = p4[1];
      const float4 v = p4[2];
      const float4 d = p4[3];
      const float af[4] = {a.x, a.y, a.z, a.w};
      const float hf[4] = {h.x, h.y, h.z, h.w};
      const float vf[4] = {v.x, v.y, v.z, v.w};
      const float df[4] = {d.x, d.y, d.z, d.w};
      const float ly0 = Lw[0][sy], ly1 = Lw[1][sy];
      const float hy0 = Hw[0][sy], hy1 = Hw[1][sy];
#pragma unroll
      for (int c = 0; c < 4; ++c) {
        lo[0][c] = fmaf(ly0, af[c], fmaf(hy0, hf[c], lo[0][c]));
        lo[1][c] = fmaf(ly1, af[c], fmaf(hy1, hf[c], lo[1][c]));
        hi[0][c] = fmaf(ly0, vf[c], fmaf(hy0, df[c], hi[0][c]));
        hi[1][c] = fmaf(ly1, vf[c], fmaf(hy1, df[c], hi[1][c]));
      }
    }

    const float lx0 = Lw[0][sx], lx1 = Lw[1][sx];
    const float hx0 = Hw[0][sx], hx1 = Hw[1][sx];
#pragma unroll
    for (int p = 0; p < 2; ++p)
#pragma unroll
      for (int c = 0; c < 4; ++c) {
        acc[p][0][c] = fmaf(lx0, lo[p][c], fmaf(hx0, hi[p][c], acc[p][0][c]));
        acc[p][1][c] = fmaf(lx1, lo[p][c], fmaf(hx1, hi[p][c], acc[p][1][c]));
      }
  }

  // Store: out[b][2jy+py][2jx+px][0..3] as float4.
  float4* ob = reinterpret_cast<float4*>(out);
  const int OY = 2 * N, OX = 2 * N;
#pragma unroll
  for (int p = 0; p < 2; ++p) {
#pragma unroll
    for (int q = 0; q < 2; ++q) {
      const size_t o = ((size_t)b * OY + (2 * jy + p)) * OX + (2 * jx + q);
      float4 r;
      r.x = acc[p][q][0];
      r.y = acc[p][q][1];
      r.z = acc[p][q][2];
      r.w = acc[p][q][3];
      ob[o] = r;
    }
  }
}

extern "C" void kernel_launch(void* const* d_in, const int* in_sizes, int n_in,
                              void* d_out, int out_size, void* d_ws,
                              size_t ws_size, hipStream_t stream) {
  const float* x = reinterpret_cast<const float*>(d_in[0]);
  float* out = reinterpret_cast<float*>(d_out);
  // 64 * 256 * 256 threads, 256/block
  const int total = 64 * 256 * 256;
  const int block = 256;
  const int grid = total / block;  // 16384
  idwt2_db4_kernel<<<grid, block, 0, stream>>>(x, out);
}

// Round 2
// 186.873 us; speedup vs baseline: 1.7694x; 1.7694x over previous
//
#include <hip/hip_runtime.h>

// IDWT2D db4, periodized. Input x: [64][256][256][16] f32 (cA|cH|cV|cD x 4ch),
// output: [64][512][512][4] f32.
//
// out[b, 2jy+py, 2jx+px, ch] =
//   sum_{sy,sx=0..3} Lx[px][sx]*(Ly[py][sy]*cA + Hy[py][sy]*cH)
//                  + Hx[px][sx]*(Ly[py][sy]*cV + Hy[py][sy]*cD)
//   at input pixel ((jy+sy)&255, (jx+sx)&255).
//
// R1: LDS-tiled. Each block: 16x16 j-tile, stages 19x19 pixels (x 4 float4
// subbands) into LDS with bulk coalesced loads, then computes from LDS.
// Row stride 77 f4-units (odd) -> ds_read_b128 spreads over all 8 bank groups.

#define TILE 16
#define HALO 3
#define ROWS (TILE + HALO)          // 19
#define ROW_F4 (ROWS * 4)           // 76 f4 per row (19 px * 4 subband-f4)
#define ROW_F4_PAD (ROW_F4 + 1)     // 77 (odd -> bank spread)
#define NF4 (ROWS * ROW_F4)         // 1444 f4 to stage

__global__ __launch_bounds__(256) void idwt2_db4_kernel(
    const float* __restrict__ x, float* __restrict__ out) {
  constexpr int N = 256;  // input spatial size

  constexpr float LO[8] = {
      0.23037781330885523f,  0.7148465705525415f,  0.6308807679295904f,
      -0.02798376941698385f, -0.18703481171888114f, 0.030841381835986965f,
      0.032883011666982945f, -0.010597401784997278f};
  constexpr float HIW[8] = {
      -0.010597401784997278f, -0.032883011666982945f, 0.030841381835986965f,
      0.18703481171888114f,  -0.02798376941698385f,  -0.6308807679295904f,
      0.7148465705525415f,   -0.23037781330885523f};

  const float Lw[2][4] = {{LO[6], LO[4], LO[2], LO[0]},
                          {LO[7], LO[5], LO[3], LO[1]}};
  const float Hw[2][4] = {{HIW[6], HIW[4], HIW[2], HIW[0]},
                          {HIW[7], HIW[5], HIW[3], HIW[1]}};

  __shared__ float4 lds[ROWS * ROW_F4_PAD];

  const int tid = threadIdx.x;
  const int bx = blockIdx.x;
  const int tileIdx = bx & 255;   // 16x16 tiles per batch
  const int b = bx >> 8;
  const int c0 = (tileIdx & 15) * TILE;
  const int r0 = (tileIdx >> 4) * TILE;

  const float4* xb = reinterpret_cast<const float4*>(x) + (size_t)b * N * N * 4;

  // ---- Stage 19x19 px * 4 f4 into LDS (coalesced, wrap via &255) ----
#pragma unroll
  for (int k = 0; k < 6; ++k) {
    const int i = tid + k * 256;
    if (k < 5 || i < NF4) {
      const int r = i / ROW_F4;          // magic-mul div
      const int w = i - r * ROW_F4;      // 0..75
      const int gr = (r0 + r) & (N - 1);
      const int gc = (c0 + (w >> 2)) & (N - 1);
      const int s = w & 3;
      lds[r * ROW_F4_PAD + w] = xb[(((gr << 8) | gc) << 2) + s];
    }
  }
  __syncthreads();

  // ---- Compute 1 j-pixel (2x2 output px * 4ch) per thread ----
  const int lx = tid & 15;
  const int ly = tid >> 4;

  float acc[2][2][4];
#pragma unroll
  for (int p = 0; p < 2; ++p)
#pragma unroll
    for (int q = 0; q < 2; ++q)
#pragma unroll
      for (int c = 0; c < 4; ++c) acc[p][q][c] = 0.0f;

#pragma unroll
  for (int sx = 0; sx < 4; ++sx) {
    float lo[2][4], hi[2][4];
#pragma unroll
    for (int p = 0; p < 2; ++p)
#pragma unroll
      for (int c = 0; c < 4; ++c) {
        lo[p][c] = 0.0f;
        hi[p][c] = 0.0f;
      }

#pragma unroll
    for (int sy = 0; sy < 4; ++sy) {
      const float4* p4 = &lds[(ly + sy) * ROW_F4_PAD + (lx + sx) * 4];
      const float4 a = p4[0];
      const float4 h = p4[1];
      const float4 v = p4[2];
      const float4 d = p4[3];
      const float af[4] = {a.x, a.y, a.z, a.w};
      const float hf[4] = {h.x, h.y, h.z, h.w};
      const float vf[4] = {v.x, v.y, v.z, v.w};
      const float df[4] = {d.x, d.y, d.z, d.w};
      const float ly0 = Lw[0][sy], ly1 = Lw[1][sy];
      const float hy0 = Hw[0][sy], hy1 = Hw[1][sy];
#pragma unroll
      for (int c = 0; c < 4; ++c) {
        lo[0][c] = fmaf(ly0, af[c], fmaf(hy0, hf[c], lo[0][c]));
        lo[1][c] = fmaf(ly1, af[c], fmaf(hy1, hf[c], lo[1][c]));
        hi[0][c] = fmaf(ly0, vf[c], fmaf(hy0, df[c], hi[0][c]));
        hi[1][c] = fmaf(ly1, vf[c], fmaf(hy1, df[c], hi[1][c]));
      }
    }

    const float lx0 = Lw[0][sx], lx1 = Lw[1][sx];
    const float hx0 = Hw[0][sx], hx1 = Hw[1][sx];
#pragma unroll
    for (int p = 0; p < 2; ++p)
#pragma unroll
      for (int c = 0; c < 4; ++c) {
        acc[p][0][c] = fmaf(lx0, lo[p][c], fmaf(hx0, hi[p][c], acc[p][0][c]));
        acc[p][1][c] = fmaf(lx1, lo[p][c], fmaf(hx1, hi[p][c], acc[p][1][c]));
      }
  }

  // ---- Store 2x2 output px (float4 each) ----
  float4* ob = reinterpret_cast<float4*>(out);
  const int OX = 2 * N;
  const int jy = r0 + ly;
  const int jx = c0 + lx;
#pragma unroll
  for (int p = 0; p < 2; ++p) {
#pragma unroll
    for (int q = 0; q < 2; ++q) {
      const size_t o = ((size_t)b * OX + (2 * jy + p)) * OX + (2 * jx + q);
      float4 r;
      r.x = acc[p][q][0];
      r.y = acc[p][q][1];
      r.z = acc[p][q][2];
      r.w = acc[p][q][3];
      ob[o] = r;
    }
  }
}

extern "C" void kernel_launch(void* const* d_in, const int* in_sizes, int n_in,
                              void* d_out, int out_size, void* d_ws,
                              size_t ws_size, hipStream_t stream) {
  const float* x = reinterpret_cast<const float*>(d_in[0]);
  float* out = reinterpret_cast<float*>(d_out);
  const int grid = 64 * 16 * 16;  // 16384 blocks: 16x16 tiles x 64 batches
  idwt2_db4_kernel<<<grid, 256, 0, stream>>>(x, out);
}

// Round 3
// 120.508 us; speedup vs baseline: 2.7439x; 1.5507x over previous
//
#include <hip/hip_runtime.h>

// IDWT2D db4, periodized. Input x: [64][256][256][16] f32 (cA|cH|cV|cD x 4ch),
// output: [64][512][512][4] f32.
//
// out[b, 2jy+p, 2jx+q, c] =
//   sum_s Lw[q][s] * lo[p][(jx+s)&255][c] + Hw[q][s] * hi[p][(jx+s)&255][c]
// lo[p][x][c] = sum_sy Lw[p][sy]*cA[(jy+sy)&255][x][c] + Hw[p][sy]*cH[...]
// hi[p][x][c] = same with cV, cD.   Lw[p][s] = REC_LO[6-2s+p], Hw likewise.
//
// R2: separable two-pass per block. Block = 8 j-rows x full 256 cols,
// 512 threads. Pass1: y-filter from global via 4-row register sliding
// window (threads t<256 do lo from A,H; t>=256 do hi from V,D), write
// intermediate I to LDS (double-buffered, 32 KB). Pass2: x-filter from
// LDS (lane-contiguous b128 reads, conflict-free) -> dense f4 stores.

#define RJ 8
#define N 256

__device__ __forceinline__ void fma4(float4& d, float s, const float4 a) {
  d.x = fmaf(s, a.x, d.x);
  d.y = fmaf(s, a.y, d.y);
  d.z = fmaf(s, a.z, d.z);
  d.w = fmaf(s, a.w, d.w);
}

__global__ __launch_bounds__(512, 4) void idwt2_sep_kernel(
    const float* __restrict__ x, float* __restrict__ out) {
  constexpr float LO[8] = {
      0.23037781330885523f,  0.7148465705525415f,  0.6308807679295904f,
      -0.02798376941698385f, -0.18703481171888114f, 0.030841381835986965f,
      0.032883011666982945f, -0.010597401784997278f};
  constexpr float HIW[8] = {
      -0.010597401784997278f, -0.032883011666982945f, 0.030841381835986965f,
      0.18703481171888114f,  -0.02798376941698385f,  -0.6308807679295904f,
      0.7148465705525415f,   -0.23037781330885523f};
  const float Lw[2][4] = {{LO[6], LO[4], LO[2], LO[0]},
                          {LO[7], LO[5], LO[3], LO[1]}};
  const float Hw[2][4] = {{HIW[6], HIW[4], HIW[2], HIW[0]},
                          {HIW[7], HIW[5], HIW[3], HIW[1]}};

  __shared__ float4 I[2][2][2][N];  // [buf][parity p][lo/hi][col], 32 KB

  const int t = threadIdx.x;
  const int tcol = t & (N - 1);
  const int thalf = t >> 8;  // 0: lo (A,H), 1: hi (V,D)
  const int rg = blockIdx.x & 31;
  const int b = blockIdx.x >> 5;
  const int r0 = rg * RJ;

  const float4* xb =
      reinterpret_cast<const float4*>(x) + (size_t)b * N * N * 4;
  float4* ob = reinterpret_cast<float4*>(out) + (size_t)b * (2 * N) * (2 * N);

  // This thread's input column pointer: pixel (row, tcol), subbands
  // {2*thalf, 2*thalf+1}. Row stride = N*4 f4.
  const float4* xcolp = xb + (size_t)tcol * 4 + thalf * 2;

  // 4-row register sliding window.
  float4 wa[4], wb_[4];
#pragma unroll
  for (int i = 0; i < 4; ++i) {
    const int gr = (r0 + i) & (N - 1);
    wa[i] = xcolp[(size_t)gr * (N * 4)];
    wb_[i] = xcolp[(size_t)gr * (N * 4) + 1];
  }

  // Pass-1 compute for j-row r0+i (window slots (i+sy)&3).
  auto p1_compute = [&](int i, float4& v0, float4& v1) {
#pragma unroll
    for (int sy = 0; sy < 4; ++sy) {
      const float4 a = wa[(i + sy) & 3];
      const float4 bb = wb_[(i + sy) & 3];
      if (sy == 0) {
        v0 = make_float4(Lw[0][0] * a.x, Lw[0][0] * a.y, Lw[0][0] * a.z,
                         Lw[0][0] * a.w);
        v1 = make_float4(Lw[1][0] * a.x, Lw[1][0] * a.y, Lw[1][0] * a.z,
                         Lw[1][0] * a.w);
        fma4(v0, Hw[0][0], bb);
        fma4(v1, Hw[1][0], bb);
      } else {
        fma4(v0, Lw[0][sy], a);
        fma4(v0, Hw[0][sy], bb);
        fma4(v1, Lw[1][sy], a);
        fma4(v1, Hw[1][sy], bb);
      }
    }
  };

  // Prologue: P1(0) -> I[0]
  {
    float4 v0, v1;
    p1_compute(0, v0, v1);
    I[0][0][thalf][tcol] = v0;
    I[0][1][thalf][tcol] = v1;
  }
  __syncthreads();

  const int jx = t >> 1;  // 0..255
  const int q = t & 1;

#pragma unroll
  for (int i = 0; i < RJ; ++i) {
    // Issue next window row load early (row r0+i+4 -> slot i&3),
    // hidden under Pass-2 compute.
    if (i < RJ - 1) {
      const int gr = (r0 + i + 4) & (N - 1);
      wa[i & 3] = xcolp[(size_t)gr * (N * 4)];
      wb_[i & 3] = xcolp[(size_t)gr * (N * 4) + 1];
    }

    // ---- Pass 2: x-filter j-row r0+i from I[i&1] ----
    float4 o0 = make_float4(0.f, 0.f, 0.f, 0.f);
    float4 o1 = make_float4(0.f, 0.f, 0.f, 0.f);
#pragma unroll
    for (int s = 0; s < 4; ++s) {
      const int xc = (jx + s) & (N - 1);
      const float lq = q ? Lw[1][s] : Lw[0][s];
      const float hq = q ? Hw[1][s] : Hw[0][s];
      fma4(o0, lq, I[i & 1][0][0][xc]);
      fma4(o0, hq, I[i & 1][0][1][xc]);
      fma4(o1, lq, I[i & 1][1][0][xc]);
      fma4(o1, hq, I[i & 1][1][1][xc]);
    }
    const int orow = 2 * (r0 + i);
    ob[(size_t)orow * (2 * N) + t] = o0;        // col f4 = 2*jx+q = t
    ob[(size_t)(orow + 1) * (2 * N) + t] = o1;

    // ---- Pass 1 for next j-row -> other buffer ----
    if (i < RJ - 1) {
      float4 v0, v1;
      p1_compute(i + 1, v0, v1);
      I[(i + 1) & 1][0][thalf][tcol] = v0;
      I[(i + 1) & 1][1][thalf][tcol] = v1;
      __syncthreads();
    }
  }
}

extern "C" void kernel_launch(void* const* d_in, const int* in_sizes, int n_in,
                              void* d_out, int out_size, void* d_ws,
                              size_t ws_size, hipStream_t stream) {
  const float* x = reinterpret_cast<const float*>(d_in[0]);
  float* out = reinterpret_cast<float*>(d_out);
  const int grid = 64 * (N / RJ);  // 2048 blocks
  idwt2_sep_kernel<<<grid, 512, 0, stream>>>(x, out);
}